// Round 1
// 738.028 us; speedup vs baseline: 1.0443x; 1.0443x over previous
//
#include <hip/hip_runtime.h>
#include <hip/hip_bf16.h>
#include <hip/hip_fp16.h>

// Problem constants (TempoAttention: N=8, T=1024, D=128, H=8)
#define NB 8
#define TT 1024
#define DD 128
#define HH 8

using short8  = __attribute__((ext_vector_type(8))) short;    // 8 bf16 (4 VGPRs)
using floatx4 = __attribute__((ext_vector_type(4))) float;    // MFMA C/D
using half8   = __attribute__((ext_vector_type(8))) _Float16;
using half4   = __attribute__((ext_vector_type(4))) _Float16; // packed b64 LDS store
using intx4   = __attribute__((ext_vector_type(4))) int;

// fp32 -> bf16 (RNE)
__device__ __forceinline__ unsigned short f2bf_u(float f) {
    union { float f; unsigned u; } v; v.f = f;
    return (unsigned short)((v.u + 0x7fffu + ((v.u >> 16) & 1u)) >> 16);
}

// ---------------------------------------------------------------------------
// Projection kernel: q = x@Wq^T+bq etc. -> bf16 in MFMA-friendly layouts.
//   q,k : [n,h,t,d]  (row = token, contiguous d)
//   v   : [n,h,d,t]  (transposed so PV B-fragments are contiguous along t)
// GEMM M=8192 (n,t), N=1024 (h*d), K=128. block = 4 waves x 16 rows, 128 cols.
// VERIFIED (outputs 0/1 passed R1) — do not touch.
// ---------------------------------------------------------------------------
__global__ __launch_bounds__(256, 2) void proj_kernel(
    const float* __restrict__ x,
    const float* __restrict__ Wq, const float* __restrict__ bq,
    const float* __restrict__ Wk, const float* __restrict__ bk,
    const float* __restrict__ Wv, const float* __restrict__ bv,
    unsigned short* __restrict__ qb, unsigned short* __restrict__ kb,
    unsigned short* __restrict__ vt)
{
    int b     = blockIdx.x;
    int which = b >> 10;          // 0=q 1=k 2=v
    int rem   = b & 1023;
    int mblk  = rem >> 3;         // 0..127 (64 rows each)
    int nblk  = rem & 7;          // 0..7   (128 cols each)
    int tid   = threadIdx.x;
    int wid   = tid >> 6, lane = tid & 63;
    int l15   = lane & 15, quad = lane >> 4;
    int m0    = mblk * 64 + wid * 16;

    const float* W    = (which == 0) ? Wq : (which == 1) ? Wk : Wv;
    const float* bias = (which == 0) ? bq : (which == 1) ? bk : bv;
    unsigned short* dst = (which == 0) ? qb : (which == 1) ? kb : vt;

    // A fragments: x rows (fp32 -> bf16), A[m=l15][k=quad*8+j]
    short8 a[4];
    const float* xr = x + (size_t)(m0 + l15) * DD + quad * 8;
    #pragma unroll
    for (int kk = 0; kk < 4; ++kk) {
        const float* p = xr + kk * 32;
        short8 t;
        #pragma unroll
        for (int j = 0; j < 8; ++j) t[j] = (short)f2bf_u(p[j]);
        a[kk] = t;
    }

    floatx4 acc[8];
    #pragma unroll
    for (int ct = 0; ct < 8; ++ct) acc[ct] = (floatx4){0.f, 0.f, 0.f, 0.f};

    for (int ct = 0; ct < 8; ++ct) {
        int c = nblk * 128 + ct * 16 + l15;          // output channel (B n-index)
        const float* wr = W + (size_t)c * DD + quad * 8;
        #pragma unroll
        for (int kk = 0; kk < 4; ++kk) {
            const float* p = wr + kk * 32;
            short8 bf;
            #pragma unroll
            for (int j = 0; j < 8; ++j) bf[j] = (short)f2bf_u(p[j]);
            acc[ct] = __builtin_amdgcn_mfma_f32_16x16x32_bf16(a[kk], bf, acc[ct], 0, 0, 0);
        }
    }

    // Epilogue: C/D layout col=l15, row=quad*4+r
    #pragma unroll
    for (int ct = 0; ct < 8; ++ct) {
        int c  = nblk * 128 + ct * 16 + l15;
        int h  = c >> 7, dd = c & 127;
        float bsv = bias[c];
        #pragma unroll
        for (int r = 0; r < 4; ++r) {
            int m = m0 + quad * 4 + r;
            int n = m >> 10, t = m & 1023;
            unsigned short v = f2bf_u(acc[ct][r] + bsv);
            size_t idx;
            if (which == 2) idx = ((size_t)(n * HH + h) * DD + dd) * TT + t;   // v^T
            else            idx = ((size_t)(n * HH + h) * TT + t) * DD + dd;   // q,k
            dst[idx] = v;
        }
    }
}

// ---------------------------------------------------------------------------
// Fused attention kernel. One block = (n,h) x 32 query rows. 256 threads.
// LDS: S[32][1032] fp16 scores (overwritten with bf16 e-bits) + rowinv.
//
// R2 changes (theory: latency-starved, MLP ~32 B/lane in flight):
//  * QK^T operand swap: mfma(K,Q) -> score frag has col=l15=query,
//    row=quad*4+r=key, so w/mask per lane are CONTIGUOUS -> float4/int4 loads.
//  * 2-deep software pipeline on the wts HBM stream, 1-deep on K.
//  * LDS score store packed to one ds_write_b64 per tile (was 8x b16).
//  * Phase 2: score row cached in regs (1 LDS pass, not 3), 8-way ILP
//    max/sum reductions (was 128-long serial chains).
//  * Phase 3: 1-deep prefetch of V (global) and P (LDS) fragments.
//  * Nontemporal stores for att/out (pure streams; keep wts L3-resident).
// Math identical: same MFMA values, same -65504 sentinel, same fp16/bf16 path.
// ---------------------------------------------------------------------------
#define SSTRIDE 1032  // halves; +8 pad breaks power-of-2 bank aliasing

__global__ __launch_bounds__(256, 2) void attn_kernel(
    const unsigned short* __restrict__ qb, const unsigned short* __restrict__ kb,
    const unsigned short* __restrict__ vt,
    const float* __restrict__ wts, const int* __restrict__ mask,
    float* __restrict__ out, float* __restrict__ outagg, float* __restrict__ att)
{
    extern __shared__ char smem[];
    _Float16* S   = (_Float16*)smem;
    float* rowinv = (float*)(smem + 32 * SSTRIDE * 2);

    // XCD swizzle: all 32 tiles of one (n,h) group land on one XCD (b%8)
    int b    = blockIdx.x;
    int slot = b & 7, j = b >> 3;
    int tile = j & 31, gq = j >> 5;
    int g    = gq * 8 + slot;          // n*H + h, 0..63
    int n    = g >> 3, h = g & 7;
    int t0   = tile * 32;

    int tid = threadIdx.x;
    int wid = tid >> 6, lane = tid & 63;
    int l15 = lane & 15, quad = lane >> 4;

    const unsigned short* qp = qb + ((size_t)g * TT + t0) * DD;
    const unsigned short* kp = kb + (size_t)g * TT * DD;
    const unsigned short* vp = vt + (size_t)g * DD * TT;
    const float* wp = wts + (size_t)g * TT * TT + (size_t)t0 * TT;
    const int*   mp = mask + n * TT;
    float* attp = att + (size_t)g * TT * TT + (size_t)t0 * TT;

    // ---- Phase 1: S = mask(weights * scale * (Q K^T)) ----
    // Q fragments (B operand now: B[n=query=l15][k=quad*8+j]) — loads unchanged.
    short8 aq[2][4];
    #pragma unroll
    for (int rt = 0; rt < 2; ++rt)
        #pragma unroll
        for (int kk = 0; kk < 4; ++kk)
            aq[rt][kk] = *(const short8*)(qp + (size_t)(rt * 16 + l15) * DD + kk * 32 + quad * 8);

    const int c0 = wid * 256;                 // each wave owns a 256-key strip
    const float scale = 0.08838834764831845f; // 1/sqrt(128)

    // Per-lane base pointers for the swapped layout.
    const float* wrow0 = wp + (size_t)l15 * TT + c0 + quad * 4;         // w[query=l15][key..]
    const float* wrow1 = wrow0 + (size_t)16 * TT;                       // queries +16
    const unsigned short* kcol = kp + (size_t)(c0 + l15) * DD + quad * 8; // K[key=l15][d..]
    const int* mrow = mp + c0 + quad * 4;
    _Float16* sst0 = S + (size_t)l15 * SSTRIDE + c0 + quad * 4;
    _Float16* sst1 = sst0 + (size_t)16 * SSTRIDE;

    // Software pipeline: w/mask 2 tiles ahead (HBM/L3 stream), K 1 tile ahead (L2).
    floatx4 w0_c, w1_c, w0_n, w1_n;
    intx4   mk_c, mk_n;
    short8  kf[4];

    w0_c = *(const floatx4*)(wrow0);
    w1_c = *(const floatx4*)(wrow1);
    mk_c = *(const intx4*)(mrow);
    w0_n = *(const floatx4*)(wrow0 + 16);
    w1_n = *(const floatx4*)(wrow1 + 16);
    mk_n = *(const intx4*)(mrow + 16);
    #pragma unroll
    for (int kk = 0; kk < 4; ++kk)
        kf[kk] = *(const short8*)(kcol + kk * 32);

    for (int ct = 0; ct < 16; ++ct) {
        // Prefetch (clamped addresses, branch-free so vmcnt stays counted).
        int ctk = (ct + 1 < 16) ? ct + 1 : 15;   // K tile ct+1
        int ctw = (ct + 2 < 16) ? ct + 2 : 15;   // w/mask tile ct+2
        short8 kn[4];
        #pragma unroll
        for (int kk = 0; kk < 4; ++kk)
            kn[kk] = *(const short8*)(kcol + ctk * 16 * DD + kk * 32);
        floatx4 nw0 = *(const floatx4*)(wrow0 + ctw * 16);
        floatx4 nw1 = *(const floatx4*)(wrow1 + ctw * 16);
        intx4   nmk = *(const intx4*)(mrow + ctw * 16);

        // Swapped MFMA: D[m=key][n=query] -> col=l15=query, row=quad*4+r=key.
        floatx4 acc0 = {0.f,0.f,0.f,0.f}, acc1 = {0.f,0.f,0.f,0.f};
        #pragma unroll
        for (int kk = 0; kk < 4; ++kk) {
            acc0 = __builtin_amdgcn_mfma_f32_16x16x32_bf16(kf[kk], aq[0][kk], acc0, 0, 0, 0);
            acc1 = __builtin_amdgcn_mfma_f32_16x16x32_bf16(kf[kk], aq[1][kk], acc1, 0, 0, 0);
        }

        // Epilogue: 4 consecutive keys per lane -> packed b64 LDS store.
        half4 h0, h1;
        #pragma unroll
        for (int r = 0; r < 4; ++r) {
            h0[r] = (_Float16)(mk_c[r] ? -65504.f : acc0[r] * scale * w0_c[r]);
            h1[r] = (_Float16)(mk_c[r] ? -65504.f : acc1[r] * scale * w1_c[r]);
        }
        *(half4*)(sst0 + ct * 16) = h0;
        *(half4*)(sst1 + ct * 16) = h1;

        // Rotate pipeline registers.
        #pragma unroll
        for (int kk = 0; kk < 4; ++kk) kf[kk] = kn[kk];
        w0_c = w0_n; w1_c = w1_n; mk_c = mk_n;
        w0_n = nw0;  w1_n = nw1;  mk_n = nmk;
    }
    __syncthreads();

    // ---- Phase 2: softmax. 8 lanes per row (same wave) -> shfl reductions.
    // Score row cached in registers (single LDS pass). 8 independent
    // accumulator chains for max and sum (ILP), then tree + shfl combine.
    // Write att fp32 (nontemporal) and store bf16-e bits into S for PV.
    int row = tid >> 3;          // 0..31
    int jj  = tid & 7;           // 0..7, owns cols {jj*8 + i*64 + e}
    _Float16* Srow = S + row * SSTRIDE + jj * 8;

    half8 hv[16];
    #pragma unroll
    for (int i = 0; i < 16; ++i) hv[i] = *(const half8*)(Srow + i * 64);

    float m8[8];
    #pragma unroll
    for (int e = 0; e < 8; ++e) m8[e] = (float)hv[0][e];
    #pragma unroll
    for (int i = 1; i < 16; ++i)
        #pragma unroll
        for (int e = 0; e < 8; ++e) m8[e] = fmaxf(m8[e], (float)hv[i][e]);
    float mx = fmaxf(fmaxf(fmaxf(m8[0], m8[1]), fmaxf(m8[2], m8[3])),
                     fmaxf(fmaxf(m8[4], m8[5]), fmaxf(m8[6], m8[7])));
    mx = fmaxf(mx, __shfl_xor(mx, 1));
    mx = fmaxf(mx, __shfl_xor(mx, 2));
    mx = fmaxf(mx, __shfl_xor(mx, 4));

    float s8[8] = {0.f,0.f,0.f,0.f,0.f,0.f,0.f,0.f};
    #pragma unroll
    for (int i = 0; i < 16; ++i)
        #pragma unroll
        for (int e = 0; e < 8; ++e) s8[e] += __expf((float)hv[i][e] - mx);
    float sum = ((s8[0] + s8[1]) + (s8[2] + s8[3])) + ((s8[4] + s8[5]) + (s8[6] + s8[7]));
    sum += __shfl_xor(sum, 1);
    sum += __shfl_xor(sum, 2);
    sum += __shfl_xor(sum, 4);
    float iv = 1.f / sum;              // all 8 lanes of the row group have it
    if (jj == 0) rowinv[row] = iv;     // PV epilogue needs it per C-row

    float* arow = attp + (size_t)row * TT + jj * 8;
    #pragma unroll
    for (int i = 0; i < 16; ++i) {
        half8 ev;
        floatx4 o0, o1;
        #pragma unroll
        for (int e = 0; e < 8; ++e) {
            float ex = __expf((float)hv[i][e] - mx);
            ev[e] = __builtin_bit_cast(_Float16, f2bf_u(ex));  // bf16 bits for PV
            float a = ex * iv;                                  // full-precision att
            if (e < 4) o0[e] = a; else o1[e - 4] = a;
        }
        *(half8*)(Srow + i * 64) = ev;
        __builtin_nontemporal_store(o0, (floatx4*)(arow + i * 64));
        __builtin_nontemporal_store(o1, (floatx4*)(arow + i * 64 + 4));
    }
    __syncthreads();   // e-bits + rowinv visible to all before PV

    // ---- Phase 3: out = (e @ V) * inv_l. Each wave owns 32 of 128 d-cols ----
    // Same math as verified R1; adds 1-deep prefetch of V (global, L2) and
    // P (LDS) fragments so per-iteration latency overlaps the MFMAs.
    int c0p = wid * 32;
    const unsigned short* vrow0 = vp + (size_t)(c0p + l15) * TT + quad * 8;
    const unsigned short* vrow1 = vp + (size_t)(c0p + 16 + l15) * TT + quad * 8;
    const _Float16* sp0 = S + (size_t)l15 * SSTRIDE + quad * 8;
    const _Float16* sp1 = S + (size_t)(16 + l15) * SSTRIDE + quad * 8;

    floatx4 o00 = {0.f,0.f,0.f,0.f}, o01 = o00, o10 = o00, o11 = o00;
    short8 vb0 = *(const short8*)(vrow0);
    short8 vb1 = *(const short8*)(vrow1);
    short8 pa0 = __builtin_bit_cast(short8, *(const half8*)(sp0));
    short8 pa1 = __builtin_bit_cast(short8, *(const half8*)(sp1));

    for (int ks = 0; ks < 32; ++ks) {
        int ksn = (ks + 1 < 32) ? ks + 1 : 31;   // clamped prefetch
        short8 nv0 = *(const short8*)(vrow0 + ksn * 32);
        short8 nv1 = *(const short8*)(vrow1 + ksn * 32);
        short8 na0 = __builtin_bit_cast(short8, *(const half8*)(sp0 + ksn * 32));
        short8 na1 = __builtin_bit_cast(short8, *(const half8*)(sp1 + ksn * 32));

        o00 = __builtin_amdgcn_mfma_f32_16x16x32_bf16(pa0, vb0, o00, 0, 0, 0);
        o01 = __builtin_amdgcn_mfma_f32_16x16x32_bf16(pa0, vb1, o01, 0, 0, 0);
        o10 = __builtin_amdgcn_mfma_f32_16x16x32_bf16(pa1, vb0, o10, 0, 0, 0);
        o11 = __builtin_amdgcn_mfma_f32_16x16x32_bf16(pa1, vb1, o11, 0, 0, 0);

        vb0 = nv0; vb1 = nv1; pa0 = na0; pa1 = na1;
    }

    #pragma unroll
    for (int ct = 0; ct < 2; ++ct) {
        int col = c0p + ct * 16 + l15;     // d index 0..127
        float agg = 0.f;
        #pragma unroll
        for (int rt = 0; rt < 2; ++rt) {
            floatx4 oo = (rt == 0) ? (ct == 0 ? o00 : o01) : (ct == 0 ? o10 : o11);
            #pragma unroll
            for (int r = 0; r < 4; ++r) {
                int rw = rt * 16 + quad * 4 + r;
                float val = oo[r] * rowinv[rw];
                __builtin_nontemporal_store(
                    val, &out[((size_t)(n * TT + t0 + rw)) * (HH * DD) + h * DD + col]);
                agg += val;
            }
        }
        atomicAdd(outagg + n * (HH * DD) + h * DD + col, agg * (1.f / (float)TT));
    }
}

extern "C" void kernel_launch(void* const* d_in, const int* in_sizes, int n_in,
                              void* d_out, int out_size, void* d_ws, size_t ws_size,
                              hipStream_t stream) {
    const float* x    = (const float*)d_in[0];
    const int*   mask = (const int*)d_in[1];      // bool -> int32 (verified R1)
    const float* wts  = (const float*)d_in[2];
    const float* Wq = (const float*)d_in[3];
    const float* bq = (const float*)d_in[4];
    const float* Wk = (const float*)d_in[5];
    const float* bk = (const float*)d_in[6];
    const float* Wv = (const float*)d_in[7];
    const float* bv = (const float*)d_in[8];

    float* out    = (float*)d_out;                                  // [8,1024,1024]
    float* outagg = out + (size_t)NB * TT * HH * DD;                // [8,1024]
    float* att    = outagg + NB * HH * DD;                          // [8,8,1024,1024]

    unsigned short* qb = (unsigned short*)d_ws;                     // 16.78 MB each
    unsigned short* kb = qb + (size_t)NB * HH * TT * DD;
    unsigned short* vt = kb + (size_t)NB * HH * TT * DD;

    hipMemsetAsync(outagg, 0, (size_t)NB * HH * DD * sizeof(float), stream);
    proj_kernel<<<3072, 256, 0, stream>>>(x, Wq, bq, Wk, bk, Wv, bv, qb, kb, vt);
    attn_kernel<<<2048, 256, 32 * SSTRIDE * 2 + 128, stream>>>(
        qb, kb, vt, wts, mask, out, outagg, att);
}